// Round 7
// baseline (174.948 us; speedup 1.0000x reference)
//
#include <hip/hip_runtime.h>
#include <hip/hip_bf16.h>
#include <stdint.h>

typedef __attribute__((ext_vector_type(4))) float f32x4;
typedef __attribute__((ext_vector_type(8))) short s16x8;
typedef __attribute__((ext_vector_type(4))) unsigned int u32x4;

// ---------------- ws layout (bytes) ----------------
// spk   : u32 [40][1024][16] encoder spike bits   @ 0        (2,621,440)
// whi   : bf16 [128][512]  w_in hi                @ 2621440  (131,072)
// wlo   : bf16 [128][512]  w_in lo                @ 2752512  (131,072)
// wahi  : bf16 [32][128]   actor+critic hi        @ 3014656  (8,192)
// walo  : bf16 [32][128]   actor+critic lo        @ 3022848  (8,192)
// I     : f32 [40][1024][128]                     @ 3031040  (20,971,520)
// zbits : u64 [40][1024][2]                       @ 24002560 (655,360)
#define OFF_WHI  2621440
#define OFF_WLO  2752512
#define OFF_WAHI 3014656
#define OFF_WALO 3022848
#define OFF_I    3031040
#define OFF_ZB   24002560

__device__ __forceinline__ void lut_entry(uint32_t by, uint32_t* r) {
    uint32_t r0 = 0, r1 = 0, r2 = 0, r3 = 0;
    if (by & 1)   r0 |= 0x3F80u;
    if (by & 2)   r0 |= 0x3F800000u;
    if (by & 4)   r1 |= 0x3F80u;
    if (by & 8)   r1 |= 0x3F800000u;
    if (by & 16)  r2 |= 0x3F80u;
    if (by & 32)  r2 |= 0x3F800000u;
    if (by & 64)  r3 |= 0x3F80u;
    if (by & 128) r3 |= 0x3F800000u;
    r[0] = r0; r[1] = r1; r[2] = r2; r[3] = r3;
}

// K_A: fused weight-split (blocks >= 2048) + LIF encoder (blocks < 2048)
__global__ __launch_bounds__(256) void k_prep_enc(const float* __restrict__ x,
                                                  const float* __restrict__ w_in,
                                                  const float* __restrict__ w_actor,
                                                  const float* __restrict__ w_critic,
                                                  uint32_t* __restrict__ spk,
                                                  __hip_bfloat16* __restrict__ whi,
                                                  __hip_bfloat16* __restrict__ wlo,
                                                  __hip_bfloat16* __restrict__ wahi,
                                                  __hip_bfloat16* __restrict__ walo) {
    const int bid = blockIdx.x;
    if (bid < 2048) {
        int gid  = bid * 256 + threadIdx.x;   // 1024*512
        int b    = gid >> 9;
        int f    = gid & 511;
        int lane = threadIdx.x & 63;
        float xv  = x[b * 256 + (f & 255)];
        float cur = (f < 256) ? fmaxf(50.f * xv, 0.f) : fmaxf(-50.f * xv, 0.f);
        int wbase = (f >> 6) << 1;
        float v = 0.f;
        for (int t = 0; t < 40; ++t) {
            v = v + 0.1f * (cur - v);
            bool z = (v - 1.0f) > 0.f;
            unsigned long long m = __ballot(z);
            if (z) v = 0.f;
            if (lane == 0)
                *(unsigned long long*)&spk[(size_t)(t * 1024 + b) * 16 + wbase] = m;
        }
    } else {
        int i = (bid - 2048) * 256 + threadIdx.x;   // 65536
        float w = w_in[i];
        __hip_bfloat16 h = __float2bfloat16(w);
        whi[i] = h;
        wlo[i] = __float2bfloat16(w - __bfloat162float(h));
        if (i < 4096) {
            int a = i >> 7, j = i & 127;
            float v = (a < 18) ? w_actor[a * 128 + j] : ((a == 18) ? w_critic[j] : 0.f);
            __hip_bfloat16 vh = __float2bfloat16(v);
            wahi[i] = vh;
            walo[i] = __float2bfloat16(v - __bfloat162float(vh));
        }
    }
}

// K_B: I = spikes @ w_in.T via MFMA + LDS-transposed coalesced stores
__global__ __launch_bounds__(512, 1) void k_ingemm(const uint32_t* __restrict__ spk,
                                                   const __hip_bfloat16* __restrict__ whi,
                                                   const __hip_bfloat16* __restrict__ wlo,
                                                   float* __restrict__ I) {
    __shared__ uint32_t lut[256][4];
    __shared__ float tile[16][128];
    const int tid = threadIdx.x;
    if (tid < 256) lut_entry(tid, lut[tid]);
    const int lane = tid & 63, wid = tid >> 6;   // 8 waves
    const int fr = lane & 15, fo = lane >> 4;
    const int n0 = wid * 16;

    s16x8 bh[16], bl[16];
#pragma unroll
    for (int ks = 0; ks < 16; ++ks) {
        int off = (n0 + fr) * 512 + ks * 32 + fo * 8;
        bh[ks] = *(const s16x8*)(whi + off);
        bl[ks] = *(const s16x8*)(wlo + off);
    }
    __syncthreads();

    const int m0 = blockIdx.x * 160;
    const int srow = tid >> 5;           // 0..15 (store mapping)
    const int sc0  = (tid & 31) * 4;
    for (int mt = 0; mt < 10; ++mt) {
        int mrow = m0 + mt * 16 + fr;
        u32x4 w0 = *(const u32x4*)&spk[mrow * 16];
        u32x4 w1 = *(const u32x4*)&spk[mrow * 16 + 4];
        u32x4 w2 = *(const u32x4*)&spk[mrow * 16 + 8];
        u32x4 w3 = *(const u32x4*)&spk[mrow * 16 + 12];
        f32x4 acc = (f32x4)0.f;
#pragma unroll
        for (int ks = 0; ks < 16; ++ks) {
            uint32_t word = (ks < 4) ? w0[ks & 3] : (ks < 8) ? w1[ks & 3]
                          : (ks < 12) ? w2[ks & 3] : w3[ks & 3];
            uint32_t by = (word >> (fo * 8)) & 0xFFu;
            union { u32x4 u; s16x8 v; } cv;
            cv.u = *(const u32x4*)lut[by];
            s16x8 af = cv.v;
            acc = __builtin_amdgcn_mfma_f32_16x16x32_bf16(af, bh[ks], acc, 0, 0, 0);
            acc = __builtin_amdgcn_mfma_f32_16x16x32_bf16(af, bl[ks], acc, 0, 0, 0);
        }
        __syncthreads();                  // tile free from previous iter
#pragma unroll
        for (int r = 0; r < 4; ++r)
            tile[fo * 4 + r][n0 + fr] = acc[r];
        __syncthreads();
        f32x4 vv = *(const f32x4*)&tile[srow][sc0];
        *(f32x4*)&I[(size_t)(m0 + mt * 16 + srow) * 128 + sc0] = vv;
    }
}

// K_C: recurrent LIF. 128 thr (2 waves), 1 channel/thread, 1 batch row/block.
// Weights in 32 NAMED f32x4 (SROA-proof -> true VGPR residency).
// Masks -> SGPR via LDS + readfirstlane. Chain = ascending channel j, single acc
// (bitwise-identical to R5/R6 trajectory).
__global__ __launch_bounds__(128, 2) void k_recur(const float* __restrict__ I,
                                                  const float* __restrict__ w_rec,
                                                  unsigned long long* __restrict__ zbits) {
    __shared__ unsigned long long zx[2][2];   // [t-parity][wave]
    const int tid = threadIdx.x;
    const int h = tid;                        // channel 0..127
    const int wid = tid >> 6;
    const int lane = tid & 63;
    const int b = blockIdx.x;
    const float* wr = w_rec + h * 128;

#define LOADW(i) f32x4 w##i = *(const f32x4*)(wr + (i) * 4);
    LOADW(0)  LOADW(1)  LOADW(2)  LOADW(3)  LOADW(4)  LOADW(5)  LOADW(6)  LOADW(7)
    LOADW(8)  LOADW(9)  LOADW(10) LOADW(11) LOADW(12) LOADW(13) LOADW(14) LOADW(15)
    LOADW(16) LOADW(17) LOADW(18) LOADW(19) LOADW(20) LOADW(21) LOADW(22) LOADW(23)
    LOADW(24) LOADW(25) LOADW(26) LOADW(27) LOADW(28) LOADW(29) LOADW(30) LOADW(31)
#undef LOADW

    float v = 0.f, ci = 0.f;
    float Ih = I[(size_t)b * 128 + h];
    uint32_t ma0 = 0, ma1 = 0, mb0 = 0, mb1 = 0;    // z_{t-1} masks (uniform)
    unsigned long long* zout = zbits + (size_t)b * 2;

#define MAC4(m, base, wv)                                           \
    rec = fmaf((((m) >> ((base)    )) & 1u) ? 1.f : 0.f, wv[0], rec); \
    rec = fmaf((((m) >> ((base) + 1)) & 1u) ? 1.f : 0.f, wv[1], rec); \
    rec = fmaf((((m) >> ((base) + 2)) & 1u) ? 1.f : 0.f, wv[2], rec); \
    rec = fmaf((((m) >> ((base) + 3)) & 1u) ? 1.f : 0.f, wv[3], rec);

    for (int t = 0; t < 40; ++t) {
        int tn = (t < 39) ? t + 1 : 39;
        float nI = I[(size_t)(tn * 1024 + b) * 128 + h];

        float rec = 0.f;
        MAC4(ma0,  0, w0)  MAC4(ma0,  4, w1)  MAC4(ma0,  8, w2)  MAC4(ma0, 12, w3)
        MAC4(ma0, 16, w4)  MAC4(ma0, 20, w5)  MAC4(ma0, 24, w6)  MAC4(ma0, 28, w7)
        MAC4(ma1,  0, w8)  MAC4(ma1,  4, w9)  MAC4(ma1,  8, w10) MAC4(ma1, 12, w11)
        MAC4(ma1, 16, w12) MAC4(ma1, 20, w13) MAC4(ma1, 24, w14) MAC4(ma1, 28, w15)
        MAC4(mb0,  0, w16) MAC4(mb0,  4, w17) MAC4(mb0,  8, w18) MAC4(mb0, 12, w19)
        MAC4(mb0, 16, w20) MAC4(mb0, 20, w21) MAC4(mb0, 24, w22) MAC4(mb0, 28, w23)
        MAC4(mb1,  0, w24) MAC4(mb1,  4, w25) MAC4(mb1,  8, w26) MAC4(mb1, 12, w27)
        MAC4(mb1, 16, w28) MAC4(mb1, 20, w29) MAC4(mb1, 24, w30) MAC4(mb1, 28, w31)

        // LIF update — verbatim R5 expressions
        float vd = v + 0.1f * (ci - v);
        float id = ci - 0.2f * ci;
        bool z = (vd - 1.0f) > 0.f;
        unsigned long long m = __ballot(z);
        v = z ? 0.f : vd;
        if (lane == 0) {
            zout[(size_t)t * 2048 + wid] = m;
            zx[t & 1][wid] = m;
        }
        ci = id + Ih + rec;            // (i_dec + I_t) + rec
        Ih = nI;
        __syncthreads();
        unsigned long long M0 = zx[t & 1][0];
        unsigned long long M1 = zx[t & 1][1];
        ma0 = __builtin_amdgcn_readfirstlane((uint32_t)M0);
        ma1 = __builtin_amdgcn_readfirstlane((uint32_t)(M0 >> 32));
        mb0 = __builtin_amdgcn_readfirstlane((uint32_t)M1);
        mb1 = __builtin_amdgcn_readfirstlane((uint32_t)(M1 >> 32));
    }
#undef MAC4
}

// K_D: fused readout GEMM + LI scan + max + softmax (unchanged from R6)
__global__ __launch_bounds__(64) void k_readout(const uint32_t* __restrict__ zb,
                                                const __hip_bfloat16* __restrict__ wahi,
                                                const __hip_bfloat16* __restrict__ walo,
                                                float* __restrict__ out) {
    __shared__ uint32_t lut[256][4];
    const int lane = threadIdx.x;
    for (int i0 = lane; i0 < 256; i0 += 64) lut_entry(i0, lut[i0]);
    const int fr = lane & 15, fo = lane >> 4;
    const int b0 = blockIdx.x * 16;

    s16x8 bf[2][4][2];
#pragma unroll
    for (int ni = 0; ni < 2; ++ni)
#pragma unroll
        for (int ks = 0; ks < 4; ++ks) {
            int off = (ni * 16 + fr) * 128 + ks * 32 + fo * 8;
            bf[ni][ks][0] = *(const s16x8*)(wahi + off);
            bf[ni][ks][1] = *(const s16x8*)(walo + off);
        }
    __syncthreads();

    f32x4 va[2], ia[2], ma_[2];
#pragma unroll
    for (int ni = 0; ni < 2; ++ni) {
        va[ni] = (f32x4)0.f; ia[ni] = (f32x4)0.f; ma_[ni] = (f32x4)(-1e30f);
    }

    for (int t = 0; t < 40; ++t) {
        int m = t * 1024 + b0 + fr;
        u32x4 zw = *(const u32x4*)&zb[(size_t)m * 4];
        f32x4 acc[2];
        acc[0] = (f32x4)0.f; acc[1] = (f32x4)0.f;
#pragma unroll
        for (int ks = 0; ks < 4; ++ks) {
            uint32_t by = (zw[ks] >> (fo * 8)) & 0xFFu;
            union { u32x4 u; s16x8 v; } cv;
            cv.u = *(const u32x4*)lut[by];
            s16x8 af = cv.v;
            acc[0] = __builtin_amdgcn_mfma_f32_16x16x32_bf16(af, bf[0][ks][0], acc[0], 0, 0, 0);
            acc[0] = __builtin_amdgcn_mfma_f32_16x16x32_bf16(af, bf[0][ks][1], acc[0], 0, 0, 0);
            acc[1] = __builtin_amdgcn_mfma_f32_16x16x32_bf16(af, bf[1][ks][0], acc[1], 0, 0, 0);
            acc[1] = __builtin_amdgcn_mfma_f32_16x16x32_bf16(af, bf[1][ks][1], acc[1], 0, 0, 0);
        }
#pragma unroll
        for (int ni = 0; ni < 2; ++ni) {
            f32x4 nva = va[ni] + 0.1f * (ia[ni] - va[ni]);
            ia[ni] = ia[ni] - 0.2f * ia[ni] + acc[ni];
            va[ni] = nva;
#pragma unroll
            for (int r = 0; r < 4; ++r)
                ma_[ni][r] = fmaxf(ma_[ni][r], nva[r]);
        }
    }

#pragma unroll
    for (int r = 0; r < 4; ++r) {
        int b = b0 + fo * 4 + r;
        float x0 = ma_[0][r];
        float x1 = (fr < 2) ? ma_[1][r] : -1e30f;
        float mx = fmaxf(x0, x1);
#pragma unroll
        for (int d = 1; d < 16; d <<= 1) mx = fmaxf(mx, __shfl_xor(mx, d));
        float e0 = expf(x0 - mx);
        float e1 = (fr < 2) ? expf(ma_[1][r] - mx) : 0.f;
        float s = e0 + e1;
#pragma unroll
        for (int d = 1; d < 16; d <<= 1) s += __shfl_xor(s, d);
        out[b * 18 + fr] = e0 / s;
        if (fr < 2) out[b * 18 + 16 + fr] = e1 / s;
        if (fr == 2) out[18432 + b] = ma_[1][r];
    }
}

extern "C" void kernel_launch(void* const* d_in, const int* in_sizes, int n_in,
                              void* d_out, int out_size, void* d_ws, size_t ws_size,
                              hipStream_t stream) {
    const float* x        = (const float*)d_in[0];
    const float* w_in     = (const float*)d_in[1];
    const float* w_rec    = (const float*)d_in[2];
    const float* w_actor  = (const float*)d_in[3];
    const float* w_critic = (const float*)d_in[4];
    float* out = (float*)d_out;
    char* ws = (char*)d_ws;
    uint32_t*           spk  = (uint32_t*)ws;
    __hip_bfloat16*     whi  = (__hip_bfloat16*)(ws + OFF_WHI);
    __hip_bfloat16*     wlo  = (__hip_bfloat16*)(ws + OFF_WLO);
    __hip_bfloat16*     wahi = (__hip_bfloat16*)(ws + OFF_WAHI);
    __hip_bfloat16*     walo = (__hip_bfloat16*)(ws + OFF_WALO);
    float*              I    = (float*)(ws + OFF_I);
    unsigned long long* zb   = (unsigned long long*)(ws + OFF_ZB);

    hipLaunchKernelGGL(k_prep_enc, dim3(2304), dim3(256), 0, stream,
                       x, w_in, w_actor, w_critic, spk, whi, wlo, wahi, walo);
    hipLaunchKernelGGL(k_ingemm,   dim3(256),  dim3(512), 0, stream, spk, whi, wlo, I);
    hipLaunchKernelGGL(k_recur,    dim3(1024), dim3(128), 0, stream, I, w_rec, zb);
    hipLaunchKernelGGL(k_readout,  dim3(64),   dim3(64),  0, stream,
                       (const uint32_t*)zb, wahi, walo, out);
}

// Round 8
// 152.234 us; speedup vs baseline: 1.1492x; 1.1492x over previous
//
#include <hip/hip_runtime.h>
#include <hip/hip_bf16.h>
#include <stdint.h>

typedef __attribute__((ext_vector_type(4))) float f32x4;
typedef __attribute__((ext_vector_type(8))) short s16x8;
typedef __attribute__((ext_vector_type(4))) unsigned int u32x4;

// ---------------- ws layout (bytes) ----------------
// spk   : u32 [40][1024][16] encoder spike bits   @ 0        (2,621,440)
// whi   : bf16 [128][512]  w_in hi                @ 2621440  (131,072)
// wlo   : bf16 [128][512]  w_in lo                @ 2752512  (131,072)
// wahi  : bf16 [32][128]   actor+critic hi        @ 3014656  (8,192)
// walo  : bf16 [32][128]   actor+critic lo        @ 3022848  (8,192)
// I     : f32 [40][1024][128]                     @ 3031040  (20,971,520)
// zbits : u64 [40][1024][2]                       @ 24002560 (655,360)
#define OFF_WHI  2621440
#define OFF_WLO  2752512
#define OFF_WAHI 3014656
#define OFF_WALO 3022848
#define OFF_I    3031040
#define OFF_ZB   24002560

__device__ __forceinline__ void lut_entry(uint32_t by, uint32_t* r) {
    uint32_t r0 = 0, r1 = 0, r2 = 0, r3 = 0;
    if (by & 1)   r0 |= 0x3F80u;
    if (by & 2)   r0 |= 0x3F800000u;
    if (by & 4)   r1 |= 0x3F80u;
    if (by & 8)   r1 |= 0x3F800000u;
    if (by & 16)  r2 |= 0x3F80u;
    if (by & 32)  r2 |= 0x3F800000u;
    if (by & 64)  r3 |= 0x3F80u;
    if (by & 128) r3 |= 0x3F800000u;
    r[0] = r0; r[1] = r1; r[2] = r2; r[3] = r3;
}

// K_A: fused weight-split (blocks >= 2048) + LIF encoder (blocks < 2048)
__global__ __launch_bounds__(256) void k_prep_enc(const float* __restrict__ x,
                                                  const float* __restrict__ w_in,
                                                  const float* __restrict__ w_actor,
                                                  const float* __restrict__ w_critic,
                                                  uint32_t* __restrict__ spk,
                                                  __hip_bfloat16* __restrict__ whi,
                                                  __hip_bfloat16* __restrict__ wlo,
                                                  __hip_bfloat16* __restrict__ wahi,
                                                  __hip_bfloat16* __restrict__ walo) {
    const int bid = blockIdx.x;
    if (bid < 2048) {
        int gid  = bid * 256 + threadIdx.x;   // 1024*512
        int b    = gid >> 9;
        int f    = gid & 511;
        int lane = threadIdx.x & 63;
        float xv  = x[b * 256 + (f & 255)];
        float cur = (f < 256) ? fmaxf(50.f * xv, 0.f) : fmaxf(-50.f * xv, 0.f);
        int wbase = (f >> 6) << 1;
        float v = 0.f;
        for (int t = 0; t < 40; ++t) {
            v = v + 0.1f * (cur - v);
            bool z = (v - 1.0f) > 0.f;
            unsigned long long m = __ballot(z);
            if (z) v = 0.f;
            if (lane == 0)
                *(unsigned long long*)&spk[(size_t)(t * 1024 + b) * 16 + wbase] = m;
        }
    } else {
        int i = (bid - 2048) * 256 + threadIdx.x;   // 65536
        float w = w_in[i];
        __hip_bfloat16 h = __float2bfloat16(w);
        whi[i] = h;
        wlo[i] = __float2bfloat16(w - __bfloat162float(h));
        if (i < 4096) {
            int a = i >> 7, j = i & 127;
            float v = (a < 18) ? w_actor[a * 128 + j] : ((a == 18) ? w_critic[j] : 0.f);
            __hip_bfloat16 vh = __float2bfloat16(v);
            wahi[i] = vh;
            walo[i] = __float2bfloat16(v - __bfloat162float(vh));
        }
    }
}

// K_B: I = spikes @ w_in.T via MFMA. Named B-frags + opaque "+v" asm to force
// VGPR residency. LDS-transposed coalesced stores.
__global__ __launch_bounds__(512, 1) void k_ingemm(const uint32_t* __restrict__ spk,
                                                   const __hip_bfloat16* __restrict__ whi,
                                                   const __hip_bfloat16* __restrict__ wlo,
                                                   float* __restrict__ I) {
    __shared__ uint32_t lut[256][4];
    __shared__ float tile[16][128];
    const int tid = threadIdx.x;
    if (tid < 256) lut_entry(tid, lut[tid]);
    const int lane = tid & 63, wid = tid >> 6;   // 8 waves
    const int fr = lane & 15, fo = lane >> 4;
    const int n0 = wid * 16;

#define LOADB(i) s16x8 bh##i, bl##i; { int off = (n0 + fr) * 512 + (i) * 32 + fo * 8; \
    bh##i = *(const s16x8*)(whi + off); bl##i = *(const s16x8*)(wlo + off); }
    LOADB(0)  LOADB(1)  LOADB(2)  LOADB(3)  LOADB(4)  LOADB(5)  LOADB(6)  LOADB(7)
    LOADB(8)  LOADB(9)  LOADB(10) LOADB(11) LOADB(12) LOADB(13) LOADB(14) LOADB(15)
#undef LOADB
    asm volatile("" : "+v"(bh0), "+v"(bh1), "+v"(bh2),  "+v"(bh3),
                      "+v"(bh4), "+v"(bh5), "+v"(bh6),  "+v"(bh7),
                      "+v"(bh8), "+v"(bh9), "+v"(bh10), "+v"(bh11),
                      "+v"(bh12),"+v"(bh13),"+v"(bh14), "+v"(bh15));
    asm volatile("" : "+v"(bl0), "+v"(bl1), "+v"(bl2),  "+v"(bl3),
                      "+v"(bl4), "+v"(bl5), "+v"(bl6),  "+v"(bl7),
                      "+v"(bl8), "+v"(bl9), "+v"(bl10), "+v"(bl11),
                      "+v"(bl12),"+v"(bl13),"+v"(bl14), "+v"(bl15));
    __syncthreads();

    const int m0 = blockIdx.x * 160;
    const int srow = tid >> 5;           // 0..15
    const int sc0  = (tid & 31) * 4;
    for (int mt = 0; mt < 10; ++mt) {
        int mrow = m0 + mt * 16 + fr;
        u32x4 w0 = *(const u32x4*)&spk[mrow * 16];
        u32x4 w1 = *(const u32x4*)&spk[mrow * 16 + 4];
        u32x4 w2 = *(const u32x4*)&spk[mrow * 16 + 8];
        u32x4 w3 = *(const u32x4*)&spk[mrow * 16 + 12];
        f32x4 acc = (f32x4)0.f;
#define KSTEP(i, WSEL) { uint32_t by = ((WSEL) >> (fo * 8)) & 0xFFu; \
        union { u32x4 u; s16x8 v; } cv; cv.u = *(const u32x4*)lut[by]; \
        acc = __builtin_amdgcn_mfma_f32_16x16x32_bf16(cv.v, bh##i, acc, 0, 0, 0); \
        acc = __builtin_amdgcn_mfma_f32_16x16x32_bf16(cv.v, bl##i, acc, 0, 0, 0); }
        KSTEP(0,  w0[0]) KSTEP(1,  w0[1]) KSTEP(2,  w0[2]) KSTEP(3,  w0[3])
        KSTEP(4,  w1[0]) KSTEP(5,  w1[1]) KSTEP(6,  w1[2]) KSTEP(7,  w1[3])
        KSTEP(8,  w2[0]) KSTEP(9,  w2[1]) KSTEP(10, w2[2]) KSTEP(11, w2[3])
        KSTEP(12, w3[0]) KSTEP(13, w3[1]) KSTEP(14, w3[2]) KSTEP(15, w3[3])
#undef KSTEP
        __syncthreads();
#pragma unroll
        for (int r = 0; r < 4; ++r)
            tile[fo * 4 + r][n0 + fr] = acc[r];
        __syncthreads();
        f32x4 vv = *(const f32x4*)&tile[srow][sc0];
        *(f32x4*)&I[(size_t)(m0 + mt * 16 + srow) * 128 + sc0] = vv;
    }
}

// K_C: recurrent LIF via MFMA. 64 blocks x 256 thr (4 waves); block = 16 batch
// rows; wave w owns out-ch [w*32, w*32+32). w_rec.T as EXACT 3-way bf16 split
// (hi+lo+lo2 == w bitwise) -> rec differs from serial chain only by summation
// order (~1e-7, proven-safe scale). Masks via ballot -> LDS double buffer.
__global__ __launch_bounds__(256, 1) void k_recur(const float* __restrict__ I,
                                                  const float* __restrict__ w_rec,
                                                  unsigned long long* __restrict__ zbits) {
    __shared__ uint32_t lut[256][4];
    __shared__ uint32_t zm[2][16][4];
    const int tid = threadIdx.x;
    lut_entry(tid, lut[tid]);
    if (tid < 64) zm[0][tid >> 2][tid & 3] = 0;
    const int lane = tid & 63, w = tid >> 6;
    const int fr = lane & 15, fo = lane >> 4;
    const int n0 = w * 32;
    const int b0 = blockIdx.x * 16;
    uint32_t* zb32 = (uint32_t*)zbits;

    // B-frags: wrecT[k][n] = w_rec[n][k]; lane: n = n0+ni*16+fr, k = ks*32+fo*8+j
#define LOADW(ks, ni) s16x8 H##ks##ni, L##ks##ni, Q##ks##ni; { \
    const float* p = w_rec + (n0 + (ni) * 16 + fr) * 128 + (ks) * 32 + fo * 8; \
    _Pragma("unroll") for (int j = 0; j < 8; ++j) { \
        float f = p[j]; \
        __hip_bfloat16 hb = __float2bfloat16(f); \
        float r1 = f - __bfloat162float(hb); \
        __hip_bfloat16 lb = __float2bfloat16(r1); \
        float r2 = r1 - __bfloat162float(lb); \
        __hip_bfloat16 qb = __float2bfloat16(r2); \
        H##ks##ni[j] = (short)*(unsigned short*)&hb; \
        L##ks##ni[j] = (short)*(unsigned short*)&lb; \
        Q##ks##ni[j] = (short)*(unsigned short*)&qb; } }
    LOADW(0,0) LOADW(1,0) LOADW(2,0) LOADW(3,0)
    LOADW(0,1) LOADW(1,1) LOADW(2,1) LOADW(3,1)
#undef LOADW
    asm volatile("" : "+v"(H00), "+v"(H10), "+v"(H20), "+v"(H30),
                      "+v"(H01), "+v"(H11), "+v"(H21), "+v"(H31),
                      "+v"(L00), "+v"(L10), "+v"(L20), "+v"(L30));
    asm volatile("" : "+v"(L01), "+v"(L11), "+v"(L21), "+v"(L31),
                      "+v"(Q00), "+v"(Q10), "+v"(Q20), "+v"(Q30),
                      "+v"(Q01), "+v"(Q11), "+v"(Q21), "+v"(Q31));

    // LIF state in D-layout: lane covers rows fo*4+r, ch n0+ni*16+fr
    f32x4 v0 = (f32x4)0.f, v1 = (f32x4)0.f, c0 = (f32x4)0.f, c1 = (f32x4)0.f;

#define ILOAD(dst, t_, ni) { _Pragma("unroll") for (int r = 0; r < 4; ++r) \
    dst[r] = I[(size_t)((t_) * 1024 + b0 + fo * 4 + r) * 128 + n0 + (ni) * 16 + fr]; }
    f32x4 icur0, icur1;
    ILOAD(icur0, 0, 0) ILOAD(icur1, 0, 1)
    __syncthreads();

    for (int t = 0; t < 40; ++t) {
        int tn = (t < 39) ? t + 1 : 39;
        f32x4 inxt0, inxt1;
        ILOAD(inxt0, tn, 0) ILOAD(inxt1, tn, 1)

        // A-frags from z_{t-1} masks
        u32x4 zw = *(const u32x4*)zm[t & 1][fr];
        union { u32x4 u; s16x8 v; } a0, a1, a2, a3;
        a0.u = *(const u32x4*)lut[(zw[0] >> (fo * 8)) & 0xFFu];
        a1.u = *(const u32x4*)lut[(zw[1] >> (fo * 8)) & 0xFFu];
        a2.u = *(const u32x4*)lut[(zw[2] >> (fo * 8)) & 0xFFu];
        a3.u = *(const u32x4*)lut[(zw[3] >> (fo * 8)) & 0xFFu];

        f32x4 r0 = (f32x4)0.f, r1 = (f32x4)0.f;
#define RECK(ks, av) \
        r0 = __builtin_amdgcn_mfma_f32_16x16x32_bf16(av, H##ks##0, r0, 0, 0, 0); \
        r0 = __builtin_amdgcn_mfma_f32_16x16x32_bf16(av, L##ks##0, r0, 0, 0, 0); \
        r0 = __builtin_amdgcn_mfma_f32_16x16x32_bf16(av, Q##ks##0, r0, 0, 0, 0); \
        r1 = __builtin_amdgcn_mfma_f32_16x16x32_bf16(av, H##ks##1, r1, 0, 0, 0); \
        r1 = __builtin_amdgcn_mfma_f32_16x16x32_bf16(av, L##ks##1, r1, 0, 0, 0); \
        r1 = __builtin_amdgcn_mfma_f32_16x16x32_bf16(av, Q##ks##1, r1, 0, 0, 0);
        RECK(0, a0.v) RECK(1, a1.v) RECK(2, a2.v) RECK(3, a3.v)
#undef RECK

        // LIF update (R1/R5 expression shapes)
        f32x4 vd0 = v0 + 0.1f * (c0 - v0);
        f32x4 vd1 = v1 + 0.1f * (c1 - v1);
        f32x4 id0 = c0 - 0.2f * c0;
        f32x4 id1 = c1 - 0.2f * c1;
        unsigned long long B00, B01, B02, B03, B10, B11, B12, B13;
        bool z;
        z = (vd0[0] - 1.0f) > 0.f; B00 = __ballot(z); if (z) vd0[0] = 0.f;
        z = (vd0[1] - 1.0f) > 0.f; B01 = __ballot(z); if (z) vd0[1] = 0.f;
        z = (vd0[2] - 1.0f) > 0.f; B02 = __ballot(z); if (z) vd0[2] = 0.f;
        z = (vd0[3] - 1.0f) > 0.f; B03 = __ballot(z); if (z) vd0[3] = 0.f;
        z = (vd1[0] - 1.0f) > 0.f; B10 = __ballot(z); if (z) vd1[0] = 0.f;
        z = (vd1[1] - 1.0f) > 0.f; B11 = __ballot(z); if (z) vd1[1] = 0.f;
        z = (vd1[2] - 1.0f) > 0.f; B12 = __ballot(z); if (z) vd1[2] = 0.f;
        z = (vd1[3] - 1.0f) > 0.f; B13 = __ballot(z); if (z) vd1[3] = 0.f;
        v0 = vd0; v1 = vd1;   // vd now holds post-reset v

        if (lane < 16) {
            int m = lane, rq = m & 3, sh = (m >> 2) * 16;
            unsigned long long s0 = (rq == 0) ? B00 : (rq == 1) ? B01 : (rq == 2) ? B02 : B03;
            unsigned long long s1 = (rq == 0) ? B10 : (rq == 1) ? B11 : (rq == 2) ? B12 : B13;
            uint32_t word = ((uint32_t)(s0 >> sh) & 0xFFFFu)
                          | (((uint32_t)(s1 >> sh) & 0xFFFFu) << 16);
            zm[(t & 1) ^ 1][m][w] = word;
            zb32[((size_t)t * 1024 + b0 + m) * 4 + w] = word;
        }

        c0 = (id0 + icur0) + r0;     // (i_dec + I_t) + rec
        c1 = (id1 + icur1) + r1;
        icur0 = inxt0; icur1 = inxt1;
        __syncthreads();
    }
#undef ILOAD
}

// K_D: fused readout GEMM + LI scan + max + softmax (unchanged)
__global__ __launch_bounds__(64) void k_readout(const uint32_t* __restrict__ zb,
                                                const __hip_bfloat16* __restrict__ wahi,
                                                const __hip_bfloat16* __restrict__ walo,
                                                float* __restrict__ out) {
    __shared__ uint32_t lut[256][4];
    const int lane = threadIdx.x;
    for (int i0 = lane; i0 < 256; i0 += 64) lut_entry(i0, lut[i0]);
    const int fr = lane & 15, fo = lane >> 4;
    const int b0 = blockIdx.x * 16;

    s16x8 bf[2][4][2];
#pragma unroll
    for (int ni = 0; ni < 2; ++ni)
#pragma unroll
        for (int ks = 0; ks < 4; ++ks) {
            int off = (ni * 16 + fr) * 128 + ks * 32 + fo * 8;
            bf[ni][ks][0] = *(const s16x8*)(wahi + off);
            bf[ni][ks][1] = *(const s16x8*)(walo + off);
        }
    __syncthreads();

    f32x4 va[2], ia[2], ma_[2];
#pragma unroll
    for (int ni = 0; ni < 2; ++ni) {
        va[ni] = (f32x4)0.f; ia[ni] = (f32x4)0.f; ma_[ni] = (f32x4)(-1e30f);
    }

    for (int t = 0; t < 40; ++t) {
        int m = t * 1024 + b0 + fr;
        u32x4 zw = *(const u32x4*)&zb[(size_t)m * 4];
        f32x4 acc[2];
        acc[0] = (f32x4)0.f; acc[1] = (f32x4)0.f;
#pragma unroll
        for (int ks = 0; ks < 4; ++ks) {
            uint32_t by = (zw[ks] >> (fo * 8)) & 0xFFu;
            union { u32x4 u; s16x8 v; } cv;
            cv.u = *(const u32x4*)lut[by];
            s16x8 af = cv.v;
            acc[0] = __builtin_amdgcn_mfma_f32_16x16x32_bf16(af, bf[0][ks][0], acc[0], 0, 0, 0);
            acc[0] = __builtin_amdgcn_mfma_f32_16x16x32_bf16(af, bf[0][ks][1], acc[0], 0, 0, 0);
            acc[1] = __builtin_amdgcn_mfma_f32_16x16x32_bf16(af, bf[1][ks][0], acc[1], 0, 0, 0);
            acc[1] = __builtin_amdgcn_mfma_f32_16x16x32_bf16(af, bf[1][ks][1], acc[1], 0, 0, 0);
        }
#pragma unroll
        for (int ni = 0; ni < 2; ++ni) {
            f32x4 nva = va[ni] + 0.1f * (ia[ni] - va[ni]);
            ia[ni] = ia[ni] - 0.2f * ia[ni] + acc[ni];
            va[ni] = nva;
#pragma unroll
            for (int r = 0; r < 4; ++r)
                ma_[ni][r] = fmaxf(ma_[ni][r], nva[r]);
        }
    }

#pragma unroll
    for (int r = 0; r < 4; ++r) {
        int b = b0 + fo * 4 + r;
        float x0 = ma_[0][r];
        float x1 = (fr < 2) ? ma_[1][r] : -1e30f;
        float mx = fmaxf(x0, x1);
#pragma unroll
        for (int d = 1; d < 16; d <<= 1) mx = fmaxf(mx, __shfl_xor(mx, d));
        float e0 = expf(x0 - mx);
        float e1 = (fr < 2) ? expf(ma_[1][r] - mx) : 0.f;
        float s = e0 + e1;
#pragma unroll
        for (int d = 1; d < 16; d <<= 1) s += __shfl_xor(s, d);
        out[b * 18 + fr] = e0 / s;
        if (fr < 2) out[b * 18 + 16 + fr] = e1 / s;
        if (fr == 2) out[18432 + b] = ma_[1][r];
    }
}

extern "C" void kernel_launch(void* const* d_in, const int* in_sizes, int n_in,
                              void* d_out, int out_size, void* d_ws, size_t ws_size,
                              hipStream_t stream) {
    const float* x        = (const float*)d_in[0];
    const float* w_in     = (const float*)d_in[1];
    const float* w_rec    = (const float*)d_in[2];
    const float* w_actor  = (const float*)d_in[3];
    const float* w_critic = (const float*)d_in[4];
    float* out = (float*)d_out;
    char* ws = (char*)d_ws;
    uint32_t*           spk  = (uint32_t*)ws;
    __hip_bfloat16*     whi  = (__hip_bfloat16*)(ws + OFF_WHI);
    __hip_bfloat16*     wlo  = (__hip_bfloat16*)(ws + OFF_WLO);
    __hip_bfloat16*     wahi = (__hip_bfloat16*)(ws + OFF_WAHI);
    __hip_bfloat16*     walo = (__hip_bfloat16*)(ws + OFF_WALO);
    float*              I    = (float*)(ws + OFF_I);
    unsigned long long* zb   = (unsigned long long*)(ws + OFF_ZB);

    hipLaunchKernelGGL(k_prep_enc, dim3(2304), dim3(256), 0, stream,
                       x, w_in, w_actor, w_critic, spk, whi, wlo, wahi, walo);
    hipLaunchKernelGGL(k_ingemm,   dim3(256),  dim3(512), 0, stream, spk, whi, wlo, I);
    hipLaunchKernelGGL(k_recur,    dim3(64),   dim3(256), 0, stream, I, w_rec, zb);
    hipLaunchKernelGGL(k_readout,  dim3(64),   dim3(64),  0, stream,
                       (const uint32_t*)zb, wahi, walo, out);
}

// Round 9
// 135.040 us; speedup vs baseline: 1.2955x; 1.1273x over previous
//
#include <hip/hip_runtime.h>
#include <hip/hip_bf16.h>
#include <stdint.h>

typedef __attribute__((ext_vector_type(4))) float f32x4;
typedef __attribute__((ext_vector_type(8))) short s16x8;
typedef __attribute__((ext_vector_type(4))) unsigned int u32x4;

// ---------------- ws layout (bytes) ----------------
// spk : u32 [40][1024][16] encoder spike bits  @ 0        (2,621,440)
// I   : f32 [40][1024][128]                    @ 2621440  (20,971,520)
#define OFF_I 2621440

__device__ __forceinline__ void lut_entry(uint32_t by, uint32_t* r) {
    uint32_t r0 = 0, r1 = 0, r2 = 0, r3 = 0;
    if (by & 1)   r0 |= 0x3F80u;
    if (by & 2)   r0 |= 0x3F800000u;
    if (by & 4)   r1 |= 0x3F80u;
    if (by & 8)   r1 |= 0x3F800000u;
    if (by & 16)  r2 |= 0x3F80u;
    if (by & 32)  r2 |= 0x3F800000u;
    if (by & 64)  r3 |= 0x3F80u;
    if (by & 128) r3 |= 0x3F800000u;
    r[0] = r0; r[1] = r1; r[2] = r2; r[3] = r3;
}

// K1: constant-current LIF encoder (verbatim R5/R8 arithmetic)
__global__ __launch_bounds__(256) void k_encode(const float* __restrict__ x,
                                                uint32_t* __restrict__ spk) {
    int gid  = blockIdx.x * 256 + threadIdx.x;   // 1024*512
    int b    = gid >> 9;
    int f    = gid & 511;
    int lane = threadIdx.x & 63;
    float xv  = x[b * 256 + (f & 255)];
    float cur = (f < 256) ? fmaxf(50.f * xv, 0.f) : fmaxf(-50.f * xv, 0.f);
    int wbase = (f >> 6) << 1;
    float v = 0.f;
    for (int t = 0; t < 40; ++t) {
        v = v + 0.1f * (cur - v);
        bool z = (v - 1.0f) > 0.f;
        unsigned long long m = __ballot(z);
        if (z) v = 0.f;
        if (lane == 0)
            *(unsigned long long*)&spk[(size_t)(t * 1024 + b) * 16 + wbase] = m;
    }
}

// K2: I = spikes @ w_in.T via MFMA. w_in split hi/lo IN-REGISTER (bitwise same
// values as the old k_prep: RNE bf16 of w, then of residual). Chain order
// unchanged from R8. LDS-transposed coalesced stores.
__global__ __launch_bounds__(512, 1) void k_ingemm(const uint32_t* __restrict__ spk,
                                                   const float* __restrict__ w_in,
                                                   float* __restrict__ I) {
    __shared__ uint32_t lut[256][4];
    __shared__ float tile[16][128];
    const int tid = threadIdx.x;
    if (tid < 256) lut_entry(tid, lut[tid]);
    const int lane = tid & 63, wid = tid >> 6;   // 8 waves
    const int fr = lane & 15, fo = lane >> 4;
    const int n0 = wid * 16;

#define LOADB(i) s16x8 bh##i, bl##i; { \
    const float* p = w_in + (n0 + fr) * 512 + (i) * 32 + fo * 8; \
    f32x4 fa = *(const f32x4*)p; f32x4 fb = *(const f32x4*)(p + 4); \
    _Pragma("unroll") for (int j = 0; j < 8; ++j) { \
        float f = (j < 4) ? fa[j] : fb[j - 4]; \
        __hip_bfloat16 hb = __float2bfloat16(f); \
        float r1 = f - __bfloat162float(hb); \
        __hip_bfloat16 lb = __float2bfloat16(r1); \
        bh##i[j] = (short)*(unsigned short*)&hb; \
        bl##i[j] = (short)*(unsigned short*)&lb; } }
    LOADB(0)  LOADB(1)  LOADB(2)  LOADB(3)  LOADB(4)  LOADB(5)  LOADB(6)  LOADB(7)
    LOADB(8)  LOADB(9)  LOADB(10) LOADB(11) LOADB(12) LOADB(13) LOADB(14) LOADB(15)
#undef LOADB
    asm volatile("" : "+v"(bh0), "+v"(bh1), "+v"(bh2),  "+v"(bh3),
                      "+v"(bh4), "+v"(bh5), "+v"(bh6),  "+v"(bh7),
                      "+v"(bh8), "+v"(bh9), "+v"(bh10), "+v"(bh11),
                      "+v"(bh12),"+v"(bh13),"+v"(bh14), "+v"(bh15));
    asm volatile("" : "+v"(bl0), "+v"(bl1), "+v"(bl2),  "+v"(bl3),
                      "+v"(bl4), "+v"(bl5), "+v"(bl6),  "+v"(bl7),
                      "+v"(bl8), "+v"(bl9), "+v"(bl10), "+v"(bl11),
                      "+v"(bl12),"+v"(bl13),"+v"(bl14), "+v"(bl15));
    __syncthreads();

    const int m0 = blockIdx.x * 160;
    const int srow = tid >> 5;           // 0..15
    const int sc0  = (tid & 31) * 4;
    for (int mt = 0; mt < 10; ++mt) {
        int mrow = m0 + mt * 16 + fr;
        u32x4 w0 = *(const u32x4*)&spk[mrow * 16];
        u32x4 w1 = *(const u32x4*)&spk[mrow * 16 + 4];
        u32x4 w2 = *(const u32x4*)&spk[mrow * 16 + 8];
        u32x4 w3 = *(const u32x4*)&spk[mrow * 16 + 12];
        f32x4 acc = (f32x4)0.f;
#define KSTEP(i, WSEL) { uint32_t by = ((WSEL) >> (fo * 8)) & 0xFFu; \
        union { u32x4 u; s16x8 v; } cv; cv.u = *(const u32x4*)lut[by]; \
        acc = __builtin_amdgcn_mfma_f32_16x16x32_bf16(cv.v, bh##i, acc, 0, 0, 0); \
        acc = __builtin_amdgcn_mfma_f32_16x16x32_bf16(cv.v, bl##i, acc, 0, 0, 0); }
        KSTEP(0,  w0[0]) KSTEP(1,  w0[1]) KSTEP(2,  w0[2]) KSTEP(3,  w0[3])
        KSTEP(4,  w1[0]) KSTEP(5,  w1[1]) KSTEP(6,  w1[2]) KSTEP(7,  w1[3])
        KSTEP(8,  w2[0]) KSTEP(9,  w2[1]) KSTEP(10, w2[2]) KSTEP(11, w2[3])
        KSTEP(12, w3[0]) KSTEP(13, w3[1]) KSTEP(14, w3[2]) KSTEP(15, w3[3])
#undef KSTEP
        __syncthreads();
#pragma unroll
        for (int r = 0; r < 4; ++r)
            tile[fo * 4 + r][n0 + fr] = acc[r];
        __syncthreads();
        f32x4 vv = *(const f32x4*)&tile[srow][sc0];
        *(f32x4*)&I[(size_t)(m0 + mt * 16 + srow) * 128 + sc0] = vv;
    }
}

// K3: FUSED recurrent LIF (R8 arithmetic, bit-identical) + readout GEMM + LI
// scan + softmax. 64 blocks x 256 thr (4 waves), block = 16 batch rows.
// Recur: wave w owns out-ch [w*32,w*32+32), exact 3-way w_rec split.
// Readout: waves 0,1 additionally run the actor/critic GEMM on z_t (masks from
// LDS zm just after the per-step barrier) — one barrier/step total.
// Barrier proof: iter t reads zm[P], writes zm[1-P], BARRIER, readout reads
// zm[1-P]. Next write to zm[P] is iter t+1 (after this barrier, which orders
// it after all iter-t reads of zm[P]); next write to zm[1-P] is iter t+2
// (after iter t+1's barrier, which orders it after iter t's readout + iter
// t+1's A-build reads of zm[1-P]).
__global__ __launch_bounds__(256, 1) void k_recur_ro(const float* __restrict__ I,
                                                     const float* __restrict__ w_rec,
                                                     const float* __restrict__ w_actor,
                                                     const float* __restrict__ w_critic,
                                                     float* __restrict__ out) {
    __shared__ uint32_t lut[256][4];
    __shared__ uint32_t zm[2][16][4];
    __shared__ float smax[16][20];
    const int tid = threadIdx.x;
    lut_entry(tid, lut[tid]);
    if (tid < 64) zm[0][tid >> 2][tid & 3] = 0;
    const int lane = tid & 63, w = tid >> 6;
    const int fr = lane & 15, fo = lane >> 4;
    const int n0 = w * 32;
    const int b0 = blockIdx.x * 16;

    // recur B-frags: wrecT[k][n]; exact 3-way split (hi+lo+lo2 == w bitwise)
#define LOADW(ks, ni) s16x8 H##ks##ni, L##ks##ni, Q##ks##ni; { \
    const float* p = w_rec + (n0 + (ni) * 16 + fr) * 128 + (ks) * 32 + fo * 8; \
    _Pragma("unroll") for (int j = 0; j < 8; ++j) { \
        float f = p[j]; \
        __hip_bfloat16 hb = __float2bfloat16(f); \
        float r1 = f - __bfloat162float(hb); \
        __hip_bfloat16 lb = __float2bfloat16(r1); \
        float r2 = r1 - __bfloat162float(lb); \
        __hip_bfloat16 qb = __float2bfloat16(r2); \
        H##ks##ni[j] = (short)*(unsigned short*)&hb; \
        L##ks##ni[j] = (short)*(unsigned short*)&lb; \
        Q##ks##ni[j] = (short)*(unsigned short*)&qb; } }
    LOADW(0,0) LOADW(1,0) LOADW(2,0) LOADW(3,0)
    LOADW(0,1) LOADW(1,1) LOADW(2,1) LOADW(3,1)
#undef LOADW
    asm volatile("" : "+v"(H00), "+v"(H10), "+v"(H20), "+v"(H30),
                      "+v"(H01), "+v"(H11), "+v"(H21), "+v"(H31),
                      "+v"(L00), "+v"(L10), "+v"(L20), "+v"(L30));
    asm volatile("" : "+v"(L01), "+v"(L11), "+v"(L21), "+v"(L31),
                      "+v"(Q00), "+v"(Q10), "+v"(Q20), "+v"(Q30),
                      "+v"(Q01), "+v"(Q11), "+v"(Q21), "+v"(Q31));

    // readout B-frags on waves 0,1: a-ch = w*16+fr; rows a>=19 zero. 2-way split
    // (bitwise same as old wahi/walo). Smooth (non-spiking) path.
    s16x8 rbh[4], rbl[4];
    const int a_ch = w * 16 + fr;
    const float* asrc = (a_ch < 18) ? (w_actor + a_ch * 128)
                       : ((a_ch == 18) ? w_critic : nullptr);
#pragma unroll
    for (int ks = 0; ks < 4; ++ks) {
#pragma unroll
        for (int j = 0; j < 8; ++j) {
            float f = asrc ? asrc[ks * 32 + fo * 8 + j] : 0.f;
            __hip_bfloat16 hb = __float2bfloat16(f);
            float r1 = f - __bfloat162float(hb);
            __hip_bfloat16 lb = __float2bfloat16(r1);
            rbh[ks][j] = (short)*(unsigned short*)&hb;
            rbl[ks][j] = (short)*(unsigned short*)&lb;
        }
    }
    f32x4 rva = (f32x4)0.f, ria = (f32x4)0.f, rma = (f32x4)(-1e30f);

    // LIF state in D-layout: lane covers rows fo*4+r, ch n0+ni*16+fr
    f32x4 v0 = (f32x4)0.f, v1 = (f32x4)0.f, c0 = (f32x4)0.f, c1 = (f32x4)0.f;

#define ILOAD(dst, t_, ni) { _Pragma("unroll") for (int r = 0; r < 4; ++r) \
    dst[r] = I[(size_t)((t_) * 1024 + b0 + fo * 4 + r) * 128 + n0 + (ni) * 16 + fr]; }
    f32x4 icur0, icur1;
    ILOAD(icur0, 0, 0) ILOAD(icur1, 0, 1)
    __syncthreads();

    for (int t = 0; t < 40; ++t) {
        int tn = (t < 39) ? t + 1 : 39;
        f32x4 inxt0, inxt1;
        ILOAD(inxt0, tn, 0) ILOAD(inxt1, tn, 1)

        // A-frags from z_{t-1}
        u32x4 zw = *(const u32x4*)zm[t & 1][fr];
        union { u32x4 u; s16x8 v; } a0, a1, a2, a3;
        a0.u = *(const u32x4*)lut[(zw[0] >> (fo * 8)) & 0xFFu];
        a1.u = *(const u32x4*)lut[(zw[1] >> (fo * 8)) & 0xFFu];
        a2.u = *(const u32x4*)lut[(zw[2] >> (fo * 8)) & 0xFFu];
        a3.u = *(const u32x4*)lut[(zw[3] >> (fo * 8)) & 0xFFu];

        f32x4 r0 = (f32x4)0.f, r1 = (f32x4)0.f;
#define RECK(ks, av) \
        r0 = __builtin_amdgcn_mfma_f32_16x16x32_bf16(av, H##ks##0, r0, 0, 0, 0); \
        r0 = __builtin_amdgcn_mfma_f32_16x16x32_bf16(av, L##ks##0, r0, 0, 0, 0); \
        r0 = __builtin_amdgcn_mfma_f32_16x16x32_bf16(av, Q##ks##0, r0, 0, 0, 0); \
        r1 = __builtin_amdgcn_mfma_f32_16x16x32_bf16(av, H##ks##1, r1, 0, 0, 0); \
        r1 = __builtin_amdgcn_mfma_f32_16x16x32_bf16(av, L##ks##1, r1, 0, 0, 0); \
        r1 = __builtin_amdgcn_mfma_f32_16x16x32_bf16(av, Q##ks##1, r1, 0, 0, 0);
        RECK(0, a0.v) RECK(1, a1.v) RECK(2, a2.v) RECK(3, a3.v)
#undef RECK

        // LIF update (R8 expressions, bitwise)
        f32x4 vd0 = v0 + 0.1f * (c0 - v0);
        f32x4 vd1 = v1 + 0.1f * (c1 - v1);
        f32x4 id0 = c0 - 0.2f * c0;
        f32x4 id1 = c1 - 0.2f * c1;
        unsigned long long B00, B01, B02, B03, B10, B11, B12, B13;
        bool z;
        z = (vd0[0] - 1.0f) > 0.f; B00 = __ballot(z); if (z) vd0[0] = 0.f;
        z = (vd0[1] - 1.0f) > 0.f; B01 = __ballot(z); if (z) vd0[1] = 0.f;
        z = (vd0[2] - 1.0f) > 0.f; B02 = __ballot(z); if (z) vd0[2] = 0.f;
        z = (vd0[3] - 1.0f) > 0.f; B03 = __ballot(z); if (z) vd0[3] = 0.f;
        z = (vd1[0] - 1.0f) > 0.f; B10 = __ballot(z); if (z) vd1[0] = 0.f;
        z = (vd1[1] - 1.0f) > 0.f; B11 = __ballot(z); if (z) vd1[1] = 0.f;
        z = (vd1[2] - 1.0f) > 0.f; B12 = __ballot(z); if (z) vd1[2] = 0.f;
        z = (vd1[3] - 1.0f) > 0.f; B13 = __ballot(z); if (z) vd1[3] = 0.f;
        v0 = vd0; v1 = vd1;

        if (lane < 16) {
            int m = lane, rq = m & 3, sh = (m >> 2) * 16;
            unsigned long long s0 = (rq == 0) ? B00 : (rq == 1) ? B01 : (rq == 2) ? B02 : B03;
            unsigned long long s1 = (rq == 0) ? B10 : (rq == 1) ? B11 : (rq == 2) ? B12 : B13;
            uint32_t word = ((uint32_t)(s0 >> sh) & 0xFFFFu)
                          | (((uint32_t)(s1 >> sh) & 0xFFFFu) << 16);
            zm[(t & 1) ^ 1][m][w] = word;
        }

        c0 = (id0 + icur0) + r0;
        c1 = (id1 + icur1) + r1;
        icur0 = inxt0; icur1 = inxt1;
        __syncthreads();

        // readout on waves 0,1 with z_t (zm[(t&1)^1]); lane fr = batch row
        if (w < 2) {
            u32x4 zw2 = *(const u32x4*)zm[(t & 1) ^ 1][fr];
            f32x4 racc = (f32x4)0.f;
#pragma unroll
            for (int ks = 0; ks < 4; ++ks) {
                uint32_t by = (zw2[ks] >> (fo * 8)) & 0xFFu;
                union { u32x4 u; s16x8 v; } cv;
                cv.u = *(const u32x4*)lut[by];
                racc = __builtin_amdgcn_mfma_f32_16x16x32_bf16(cv.v, rbh[ks], racc, 0, 0, 0);
                racc = __builtin_amdgcn_mfma_f32_16x16x32_bf16(cv.v, rbl[ks], racc, 0, 0, 0);
            }
            f32x4 nva = rva + 0.1f * (ria - rva);
            ria = ria - 0.2f * ria + racc;
            rva = nva;
#pragma unroll
            for (int r = 0; r < 4; ++r)
                rma[r] = fmaxf(rma[r], nva[r]);
        }
    }
#undef ILOAD

    // gather maxima: D-layout row = fo*4+r (batch), col = a-ch
    if (w == 0) {
#pragma unroll
        for (int r = 0; r < 4; ++r) smax[fo * 4 + r][fr] = rma[r];
    } else if (w == 1 && fr < 3) {
#pragma unroll
        for (int r = 0; r < 4; ++r) smax[fo * 4 + r][16 + fr] = rma[r];
    }
    __syncthreads();
    if (tid < 16) {
        int row = tid;
        float mx = -1e30f;
#pragma unroll
        for (int a2 = 0; a2 < 18; ++a2) mx = fmaxf(mx, smax[row][a2]);
        float s = 0.f;
#pragma unroll
        for (int a2 = 0; a2 < 18; ++a2) s += expf(smax[row][a2] - mx);
#pragma unroll
        for (int a2 = 0; a2 < 18; ++a2)
            out[(b0 + row) * 18 + a2] = expf(smax[row][a2] - mx) / s;
        out[18432 + b0 + row] = smax[row][18];
    }
}

extern "C" void kernel_launch(void* const* d_in, const int* in_sizes, int n_in,
                              void* d_out, int out_size, void* d_ws, size_t ws_size,
                              hipStream_t stream) {
    const float* x        = (const float*)d_in[0];
    const float* w_in     = (const float*)d_in[1];
    const float* w_rec    = (const float*)d_in[2];
    const float* w_actor  = (const float*)d_in[3];
    const float* w_critic = (const float*)d_in[4];
    float* out = (float*)d_out;
    char* ws = (char*)d_ws;
    uint32_t* spk = (uint32_t*)ws;
    float*    I   = (float*)(ws + OFF_I);

    hipLaunchKernelGGL(k_encode,   dim3(2048), dim3(256), 0, stream, x, spk);
    hipLaunchKernelGGL(k_ingemm,   dim3(256),  dim3(512), 0, stream, spk, w_in, I);
    hipLaunchKernelGGL(k_recur_ro, dim3(64),   dim3(256), 0, stream,
                       I, w_rec, w_actor, w_critic, out);
}

// Round 11
// 129.370 us; speedup vs baseline: 1.3523x; 1.0438x over previous
//
#include <hip/hip_runtime.h>
#include <hip/hip_bf16.h>
#include <stdint.h>

typedef __attribute__((ext_vector_type(4))) float f32x4;
typedef __attribute__((ext_vector_type(8))) short s16x8;
typedef __attribute__((ext_vector_type(4))) unsigned int u32x4;

// ---------------- ws layout (bytes) ----------------
// spk : u32 [40][1024][16] encoder spike bits  @ 0        (2,621,440)
// I   : f32 [40][1024][128]                    @ 2621440  (20,971,520)
#define OFF_I 2621440

__device__ __forceinline__ void lut_entry(uint32_t by, uint32_t* r) {
    uint32_t r0 = 0, r1 = 0, r2 = 0, r3 = 0;
    if (by & 1)   r0 |= 0x3F80u;
    if (by & 2)   r0 |= 0x3F800000u;
    if (by & 4)   r1 |= 0x3F80u;
    if (by & 8)   r1 |= 0x3F800000u;
    if (by & 16)  r2 |= 0x3F80u;
    if (by & 32)  r2 |= 0x3F800000u;
    if (by & 64)  r3 |= 0x3F80u;
    if (by & 128) r3 |= 0x3F800000u;
    r[0] = r0; r[1] = r1; r[2] = r2; r[3] = r3;
}

// K1: constant-current LIF encoder (verbatim R5/R8/R9 arithmetic)
__global__ __launch_bounds__(256) void k_encode(const float* __restrict__ x,
                                                uint32_t* __restrict__ spk) {
    int gid  = blockIdx.x * 256 + threadIdx.x;   // 1024*512
    int b    = gid >> 9;
    int f    = gid & 511;
    int lane = threadIdx.x & 63;
    float xv  = x[b * 256 + (f & 255)];
    float cur = (f < 256) ? fmaxf(50.f * xv, 0.f) : fmaxf(-50.f * xv, 0.f);
    int wbase = (f >> 6) << 1;
    float v = 0.f;
    for (int t = 0; t < 40; ++t) {
        v = v + 0.1f * (cur - v);
        bool z = (v - 1.0f) > 0.f;
        unsigned long long m = __ballot(z);
        if (z) v = 0.f;
        if (lane == 0)
            *(unsigned long long*)&spk[(size_t)(t * 1024 + b) * 16 + wbase] = m;
    }
}

// K2: I = spikes @ w_in.T via MFMA (verbatim R9: in-register hi/lo split,
// chain order unchanged, LDS-transposed coalesced stores)
__global__ __launch_bounds__(512, 1) void k_ingemm(const uint32_t* __restrict__ spk,
                                                   const float* __restrict__ w_in,
                                                   float* __restrict__ I) {
    __shared__ uint32_t lut[256][4];
    __shared__ float tile[16][128];
    const int tid = threadIdx.x;
    if (tid < 256) lut_entry(tid, lut[tid]);
    const int lane = tid & 63, wid = tid >> 6;   // 8 waves
    const int fr = lane & 15, fo = lane >> 4;
    const int n0 = wid * 16;

#define LOADB(i) s16x8 bh##i, bl##i; { \
    const float* p = w_in + (n0 + fr) * 512 + (i) * 32 + fo * 8; \
    f32x4 fa = *(const f32x4*)p; f32x4 fb = *(const f32x4*)(p + 4); \
    _Pragma("unroll") for (int j = 0; j < 8; ++j) { \
        float f = (j < 4) ? fa[j] : fb[j - 4]; \
        __hip_bfloat16 hb = __float2bfloat16(f); \
        float r1 = f - __bfloat162float(hb); \
        __hip_bfloat16 lb = __float2bfloat16(r1); \
        bh##i[j] = (short)*(unsigned short*)&hb; \
        bl##i[j] = (short)*(unsigned short*)&lb; } }
    LOADB(0)  LOADB(1)  LOADB(2)  LOADB(3)  LOADB(4)  LOADB(5)  LOADB(6)  LOADB(7)
    LOADB(8)  LOADB(9)  LOADB(10) LOADB(11) LOADB(12) LOADB(13) LOADB(14) LOADB(15)
#undef LOADB
    asm volatile("" : "+v"(bh0), "+v"(bh1), "+v"(bh2),  "+v"(bh3),
                      "+v"(bh4), "+v"(bh5), "+v"(bh6),  "+v"(bh7),
                      "+v"(bh8), "+v"(bh9), "+v"(bh10), "+v"(bh11),
                      "+v"(bh12),"+v"(bh13),"+v"(bh14), "+v"(bh15));
    asm volatile("" : "+v"(bl0), "+v"(bl1), "+v"(bl2),  "+v"(bl3),
                      "+v"(bl4), "+v"(bl5), "+v"(bl6),  "+v"(bl7),
                      "+v"(bl8), "+v"(bl9), "+v"(bl10), "+v"(bl11),
                      "+v"(bl12),"+v"(bl13),"+v"(bl14), "+v"(bl15));
    __syncthreads();

    const int m0 = blockIdx.x * 160;
    const int srow = tid >> 5;           // 0..15
    const int sc0  = (tid & 31) * 4;
    for (int mt = 0; mt < 10; ++mt) {
        int mrow = m0 + mt * 16 + fr;
        u32x4 w0 = *(const u32x4*)&spk[mrow * 16];
        u32x4 w1 = *(const u32x4*)&spk[mrow * 16 + 4];
        u32x4 w2 = *(const u32x4*)&spk[mrow * 16 + 8];
        u32x4 w3 = *(const u32x4*)&spk[mrow * 16 + 12];
        f32x4 acc = (f32x4)0.f;
#define KSTEP(i, WSEL) { uint32_t by = ((WSEL) >> (fo * 8)) & 0xFFu; \
        union { u32x4 u; s16x8 v; } cv; cv.u = *(const u32x4*)lut[by]; \
        acc = __builtin_amdgcn_mfma_f32_16x16x32_bf16(cv.v, bh##i, acc, 0, 0, 0); \
        acc = __builtin_amdgcn_mfma_f32_16x16x32_bf16(cv.v, bl##i, acc, 0, 0, 0); }
        KSTEP(0,  w0[0]) KSTEP(1,  w0[1]) KSTEP(2,  w0[2]) KSTEP(3,  w0[3])
        KSTEP(4,  w1[0]) KSTEP(5,  w1[1]) KSTEP(6,  w1[2]) KSTEP(7,  w1[3])
        KSTEP(8,  w2[0]) KSTEP(9,  w2[1]) KSTEP(10, w2[2]) KSTEP(11, w2[3])
        KSTEP(12, w3[0]) KSTEP(13, w3[1]) KSTEP(14, w3[2]) KSTEP(15, w3[3])
#undef KSTEP
        __syncthreads();
#pragma unroll
        for (int r = 0; r < 4; ++r)
            tile[fo * 4 + r][n0 + fr] = acc[r];
        __syncthreads();
        f32x4 vv = *(const f32x4*)&tile[srow][sc0];
        *(f32x4*)&I[(size_t)(m0 + mt * 16 + srow) * 128 + sc0] = vv;
    }
}

// K3: FUSED recurrent LIF + readout, 8-WAVE variant. 64 blocks x 512 thr;
// block = 16 batch rows; wave w owns out-ch [w*16, w*16+16).
// Per-channel rec chain = H,L,Q per ks, ks ascending — bit-identical to R8/R9.
// zm repacked as uint16[8]/row (same bit content). Readout on waves 0,1 after
// the per-step barrier overlaps waves 2-7's next-step recur work.
__global__ __launch_bounds__(512, 1) void k_recur_ro(const float* __restrict__ I,
                                                     const float* __restrict__ w_rec,
                                                     const float* __restrict__ w_actor,
                                                     const float* __restrict__ w_critic,
                                                     float* __restrict__ out) {
    __shared__ uint32_t lut[256][4];
    __shared__ __align__(16) uint16_t zm16[2][16][8];
    __shared__ float smax[16][20];
    const int tid = threadIdx.x;
    if (tid < 256) lut_entry(tid, lut[tid]);
    if (tid < 128) ((uint16_t*)zm16)[tid] = 0;   // parity-0 masks = 0 (z init)
    const int lane = tid & 63, w = tid >> 6;      // 8 waves
    const int fr = lane & 15, fo = lane >> 4;
    const int n0 = w * 16;
    const int b0 = blockIdx.x * 16;

    // w_rec B-frags: exact 3-way split (hi+lo+lo2 == w bitwise); col n0+fr
#define LOADW(ks) s16x8 H##ks, L##ks, Q##ks; { \
    const float* p = w_rec + (n0 + fr) * 128 + (ks) * 32 + fo * 8; \
    _Pragma("unroll") for (int j = 0; j < 8; ++j) { \
        float f = p[j]; \
        __hip_bfloat16 hb = __float2bfloat16(f); \
        float r1 = f - __bfloat162float(hb); \
        __hip_bfloat16 lb = __float2bfloat16(r1); \
        float r2 = r1 - __bfloat162float(lb); \
        __hip_bfloat16 qb = __float2bfloat16(r2); \
        H##ks[j] = (short)*(unsigned short*)&hb; \
        L##ks[j] = (short)*(unsigned short*)&lb; \
        Q##ks[j] = (short)*(unsigned short*)&qb; } }
    LOADW(0) LOADW(1) LOADW(2) LOADW(3)
#undef LOADW
    asm volatile("" : "+v"(H0), "+v"(H1), "+v"(H2), "+v"(H3),
                      "+v"(L0), "+v"(L1), "+v"(L2), "+v"(L3),
                      "+v"(Q0), "+v"(Q1), "+v"(Q2), "+v"(Q3));

    // readout B-frags (waves 0,1): a-ch = w*16+fr; 2-way split; rows a>=19 zero
    s16x8 rbh[4], rbl[4];
    const int a_ch = w * 16 + fr;
    const float* asrc = (w < 2)
        ? ((a_ch < 18) ? (w_actor + a_ch * 128) : ((a_ch == 18) ? w_critic : nullptr))
        : nullptr;
#pragma unroll
    for (int ks = 0; ks < 4; ++ks) {
#pragma unroll
        for (int j = 0; j < 8; ++j) {
            float f = asrc ? asrc[ks * 32 + fo * 8 + j] : 0.f;
            __hip_bfloat16 hb = __float2bfloat16(f);
            float r1 = f - __bfloat162float(hb);
            __hip_bfloat16 lb = __float2bfloat16(r1);
            rbh[ks][j] = (short)*(unsigned short*)&hb;
            rbl[ks][j] = (short)*(unsigned short*)&lb;
        }
    }
    f32x4 rva = (f32x4)0.f, ria = (f32x4)0.f, rma = (f32x4)(-1e30f);

    // LIF state in D-layout: lane covers rows fo*4+r, ch n0+fr
    f32x4 v0 = (f32x4)0.f, c0 = (f32x4)0.f;

#define ILOAD(dst, t_) { _Pragma("unroll") for (int r = 0; r < 4; ++r) \
    dst[r] = I[(size_t)((t_) * 1024 + b0 + fo * 4 + r) * 128 + n0 + fr]; }
    f32x4 icur;
    ILOAD(icur, 0)
    __syncthreads();

    for (int t = 0; t < 40; ++t) {
        int tn = (t < 39) ? t + 1 : 39;
        f32x4 inxt;
        ILOAD(inxt, tn)

        // A-frags from z_{t-1}
        u32x4 zw = *(const u32x4*)zm16[t & 1][fr];
        union { u32x4 u; s16x8 v; } a0, a1, a2, a3;
        a0.u = *(const u32x4*)lut[(zw[0] >> (fo * 8)) & 0xFFu];
        a1.u = *(const u32x4*)lut[(zw[1] >> (fo * 8)) & 0xFFu];
        a2.u = *(const u32x4*)lut[(zw[2] >> (fo * 8)) & 0xFFu];
        a3.u = *(const u32x4*)lut[(zw[3] >> (fo * 8)) & 0xFFu];

        f32x4 r0 = (f32x4)0.f;
#define RECK(ks, av) \
        r0 = __builtin_amdgcn_mfma_f32_16x16x32_bf16(av, H##ks, r0, 0, 0, 0); \
        r0 = __builtin_amdgcn_mfma_f32_16x16x32_bf16(av, L##ks, r0, 0, 0, 0); \
        r0 = __builtin_amdgcn_mfma_f32_16x16x32_bf16(av, Q##ks, r0, 0, 0, 0);
        RECK(0, a0.v) RECK(1, a1.v) RECK(2, a2.v) RECK(3, a3.v)
#undef RECK

        // LIF update (R8/R9 expressions, bitwise)
        f32x4 vd = v0 + 0.1f * (c0 - v0);
        f32x4 id = c0 - 0.2f * c0;
        unsigned long long B0, B1, B2, B3;
        bool z;
        z = (vd[0] - 1.0f) > 0.f; B0 = __ballot(z); if (z) vd[0] = 0.f;
        z = (vd[1] - 1.0f) > 0.f; B1 = __ballot(z); if (z) vd[1] = 0.f;
        z = (vd[2] - 1.0f) > 0.f; B2 = __ballot(z); if (z) vd[2] = 0.f;
        z = (vd[3] - 1.0f) > 0.f; B3 = __ballot(z); if (z) vd[3] = 0.f;
        v0 = vd;

        if (lane < 16) {
            int m = lane, rq = m & 3, sh = (m >> 2) * 16;
            unsigned long long s = (rq == 0) ? B0 : (rq == 1) ? B1 : (rq == 2) ? B2 : B3;
            zm16[(t & 1) ^ 1][m][w] = (uint16_t)((s >> sh) & 0xFFFFu);
        }

        c0 = (id + icur) + r0;     // (i_dec + I_t) + rec
        icur = inxt;
        __syncthreads();

        // readout on waves 0,1 with z_t (zm[(t&1)^1]); lane fr = batch row
        if (w < 2) {
            u32x4 zw2 = *(const u32x4*)zm16[(t & 1) ^ 1][fr];
            f32x4 racc = (f32x4)0.f;
#pragma unroll
            for (int ks = 0; ks < 4; ++ks) {
                uint32_t by = (zw2[ks] >> (fo * 8)) & 0xFFu;
                union { u32x4 u; s16x8 v; } cv;
                cv.u = *(const u32x4*)lut[by];
                racc = __builtin_amdgcn_mfma_f32_16x16x32_bf16(cv.v, rbh[ks], racc, 0, 0, 0);
                racc = __builtin_amdgcn_mfma_f32_16x16x32_bf16(cv.v, rbl[ks], racc, 0, 0, 0);
            }
            f32x4 nva = rva + 0.1f * (ria - rva);
            ria = ria - 0.2f * ria + racc;
            rva = nva;
#pragma unroll
            for (int r = 0; r < 4; ++r)
                rma[r] = fmaxf(rma[r], nva[r]);
        }
    }
#undef ILOAD

    // gather maxima: D-layout row = fo*4+r (batch), col = a-ch
    if (w == 0) {
#pragma unroll
        for (int r = 0; r < 4; ++r) smax[fo * 4 + r][fr] = rma[r];
    } else if (w == 1 && fr < 3) {
#pragma unroll
        for (int r = 0; r < 4; ++r) smax[fo * 4 + r][16 + fr] = rma[r];
    }
    __syncthreads();
    if (tid < 16) {
        int row = tid;
        float mx = -1e30f;
#pragma unroll
        for (int a2 = 0; a2 < 18; ++a2) mx = fmaxf(mx, smax[row][a2]);
        float s = 0.f;
#pragma unroll
        for (int a2 = 0; a2 < 18; ++a2) s += expf(smax[row][a2] - mx);
#pragma unroll
        for (int a2 = 0; a2 < 18; ++a2)
            out[(b0 + row) * 18 + a2] = expf(smax[row][a2] - mx) / s;
        out[18432 + b0 + row] = smax[row][18];
    }
}

extern "C" void kernel_launch(void* const* d_in, const int* in_sizes, int n_in,
                              void* d_out, int out_size, void* d_ws, size_t ws_size,
                              hipStream_t stream) {
    const float* x        = (const float*)d_in[0];
    const float* w_in     = (const float*)d_in[1];
    const float* w_rec    = (const float*)d_in[2];
    const float* w_actor  = (const float*)d_in[3];
    const float* w_critic = (const float*)d_in[4];
    float* out = (float*)d_out;
    char* ws = (char*)d_ws;
    uint32_t* spk = (uint32_t*)ws;
    float*    I   = (float*)(ws + OFF_I);

    hipLaunchKernelGGL(k_encode,   dim3(2048), dim3(256), 0, stream, x, spk);
    hipLaunchKernelGGL(k_ingemm,   dim3(256),  dim3(512), 0, stream, spk, w_in, I);
    hipLaunchKernelGGL(k_recur_ro, dim3(64),   dim3(512), 0, stream,
                       I, w_rec, w_actor, w_critic, out);
}